// Round 12
// baseline (427.676 us; speedup 1.0000x reference)
//
#include <hip/hip_runtime.h>

typedef _Float16 f16x8 __attribute__((ext_vector_type(8)));
typedef _Float16 f16x4 __attribute__((ext_vector_type(4)));
typedef float    f32x4 __attribute__((ext_vector_type(4)));

#define BN    64           // points per block
#define KPAD  288          // padded K width for the skip layer
#define ROWB  (KPAD * 2)   // 576 bytes per LDS row
#define WELE  270336       // fp16 elements per weight bank (hi or lo)
#define LDS_ACT (2 * BN * ROWB)       // 73728 B activation buffers
#define LDS_TOTAL (LDS_ACT + 4096)    // + 4 layer biases ([4][256] f32)

// sched_group_barrier masks (LLVM SchedGroupMask)
#define SGB(mask, n) __builtin_amdgcn_sched_group_barrier((mask), (n), 0)
#define SG_MFMA   0x8
#define SG_VMEM_R 0x20
#define SG_DS_R   0x100

// XOR swizzle on the 16B-slot index for cols 0..255 (bytes 0..511).
__device__ __forceinline__ int swz(int row, int colb) {
  int c = (colb < 512) ? (colb ^ ((row & 7) << 4)) : colb;
  return row * ROWB + c;
}

__device__ __forceinline__ float gabor_f(float lin) {
  float a = 10.f * lin;                 // OMEGA == SIGMA == 10
  return __cosf(a) * __expf(-a * a);
}

// One 256-out gabor layer, split-precision weights in packed per-wave layout,
// software-pipelined 1 kk ahead on BOTH streams (W: global, B: LDS) with
// sched_group_barrier pinning per-iteration emission to
// {4 VMEM_READ, 4 DS_READ, 16 MFMA} so the compiler emits counted
// vmcnt(4)/lgkmcnt(4) waits instead of sinking the prefetches.
template <int KS>
__device__ __forceinline__ void mfma_layer(const char* __restrict__ inb,
                                           char* __restrict__ outb,
                                           const _Float16* __restrict__ Wh,
                                           const _Float16* __restrict__ Wl,
                                           const float* __restrict__ lbias,
                                           int lane, int wid, int phase) {
  const int r = lane & 15;
  const int g = lane >> 4;
  const int n0 = wid * 32;
  f32x4 acc[2][4];
#pragma unroll
  for (int i = 0; i < 2; i++)
#pragma unroll
    for (int j = 0; j < 4; j++) {
      f32x4 z = {0.f, 0.f, 0.f, 0.f};
      acc[i][j] = z;
    }

  // ping-pong operand sets (fully unrolled loop -> static indices only)
  f16x8 a0[2], a1[2], c0[2], c1[2], b[2][4];

  // prologue: issue kk=0's W loads + B reads into set 0
  {
    const int kkr = (phase >= KS) ? 0 + 0 : phase;  // kidx(0)
    const int wof = (wid * KS + kkr) * 1024 + lane * 8;
    a0[0] = *(const f16x8*)(Wh + wof);
    a1[0] = *(const f16x8*)(Wh + wof + 512);
    c0[0] = *(const f16x8*)(Wl + wof);
    c1[0] = *(const f16x8*)(Wl + wof + 512);
    const int kb = kkr * 32 + g * 8;
#pragma unroll
    for (int j = 0; j < 4; j++)
      b[0][j] = *(const f16x8*)(inb + swz(j * 16 + r, kb * 2));
    SGB(SG_VMEM_R, 4);
    SGB(SG_DS_R, 4);
  }

#pragma unroll
  for (int kk = 0; kk < KS; kk++) {
    const int cur = kk & 1;
    const int nxt = cur ^ 1;

    if (kk + 1 < KS) {                  // prefetch kk+1 (both streams)
      int kkr = kk + 1 + phase;
      if (kkr >= KS) kkr -= KS;
      const int wof = (wid * KS + kkr) * 1024 + lane * 8;
      a0[nxt] = *(const f16x8*)(Wh + wof);
      a1[nxt] = *(const f16x8*)(Wh + wof + 512);
      c0[nxt] = *(const f16x8*)(Wl + wof);
      c1[nxt] = *(const f16x8*)(Wl + wof + 512);
      const int kb = kkr * 32 + g * 8;
#pragma unroll
      for (int j = 0; j < 4; j++)
        b[nxt][j] = *(const f16x8*)(inb + swz(j * 16 + r, kb * 2));
    }

    acc[0][0] = __builtin_amdgcn_mfma_f32_16x16x32_f16(a0[cur], b[cur][0], acc[0][0], 0, 0, 0);
    acc[0][1] = __builtin_amdgcn_mfma_f32_16x16x32_f16(a0[cur], b[cur][1], acc[0][1], 0, 0, 0);
    acc[0][2] = __builtin_amdgcn_mfma_f32_16x16x32_f16(a0[cur], b[cur][2], acc[0][2], 0, 0, 0);
    acc[0][3] = __builtin_amdgcn_mfma_f32_16x16x32_f16(a0[cur], b[cur][3], acc[0][3], 0, 0, 0);
    acc[1][0] = __builtin_amdgcn_mfma_f32_16x16x32_f16(a1[cur], b[cur][0], acc[1][0], 0, 0, 0);
    acc[1][1] = __builtin_amdgcn_mfma_f32_16x16x32_f16(a1[cur], b[cur][1], acc[1][1], 0, 0, 0);
    acc[1][2] = __builtin_amdgcn_mfma_f32_16x16x32_f16(a1[cur], b[cur][2], acc[1][2], 0, 0, 0);
    acc[1][3] = __builtin_amdgcn_mfma_f32_16x16x32_f16(a1[cur], b[cur][3], acc[1][3], 0, 0, 0);
    acc[0][0] = __builtin_amdgcn_mfma_f32_16x16x32_f16(c0[cur], b[cur][0], acc[0][0], 0, 0, 0);
    acc[0][1] = __builtin_amdgcn_mfma_f32_16x16x32_f16(c0[cur], b[cur][1], acc[0][1], 0, 0, 0);
    acc[0][2] = __builtin_amdgcn_mfma_f32_16x16x32_f16(c0[cur], b[cur][2], acc[0][2], 0, 0, 0);
    acc[0][3] = __builtin_amdgcn_mfma_f32_16x16x32_f16(c0[cur], b[cur][3], acc[0][3], 0, 0, 0);
    acc[1][0] = __builtin_amdgcn_mfma_f32_16x16x32_f16(c1[cur], b[cur][0], acc[1][0], 0, 0, 0);
    acc[1][1] = __builtin_amdgcn_mfma_f32_16x16x32_f16(c1[cur], b[cur][1], acc[1][1], 0, 0, 0);
    acc[1][2] = __builtin_amdgcn_mfma_f32_16x16x32_f16(c1[cur], b[cur][2], acc[1][2], 0, 0, 0);
    acc[1][3] = __builtin_amdgcn_mfma_f32_16x16x32_f16(c1[cur], b[cur][3], acc[1][3], 0, 0, 0);

    // pin this iteration's emission: prefetches first, then the MFMA cluster
    if (kk + 1 < KS) {
      SGB(SG_VMEM_R, 4);
      SGB(SG_DS_R, 4);
    }
    SGB(SG_MFMA, 16);
  }

  // epilogue: +bias (LDS), gabor, pack 4 consecutive units -> ds_write_b64
#pragma unroll
  for (int i = 0; i < 2; i++) {
    const f32x4 bv = *(const f32x4*)(lbias + n0 + i * 16 + g * 4);
#pragma unroll
    for (int j = 0; j < 4; j++) {
      f16x4 hv;
#pragma unroll
      for (int e = 0; e < 4; e++)
        hv[e] = (_Float16)gabor_f(acc[i][j][e] + bv[e]);
      *(f16x4*)(outb + swz(j * 16 + r, (n0 + i * 16 + g * 4) * 2)) = hv;
    }
  }
}

extern "C" __global__ void __launch_bounds__(512, 4)
inr_fused(const float* __restrict__ x, const float* __restrict__ W0,
          const float* __restrict__ b0, const float* __restrict__ b1,
          const float* __restrict__ b2, const float* __restrict__ b3,
          const float* __restrict__ b4, const float* __restrict__ Wf,
          const float* __restrict__ bf, const _Float16* __restrict__ wsh,
          float* __restrict__ out, int npts) {
  extern __shared__ char smem[];
  char* bufA = smem;
  char* bufB = smem + BN * ROWB;
  float* lbias = (float*)(smem + LDS_ACT);   // [4][256]

  // packed layer bases (halves): L1 @0, L2 @65536, L4 @131072, L3 @196608
  const _Float16* w1h = wsh;
  const _Float16* w2h = wsh + 65536;
  const _Float16* w4h = wsh + 131072;
  const _Float16* w3p = wsh + 196608;
  const _Float16* w1l = wsh + WELE;
  const _Float16* w2l = wsh + WELE + 65536;
  const _Float16* w4l = wsh + WELE + 131072;
  const _Float16* w3l = wsh + WELE + 196608;

  const int tid   = threadIdx.x;
  const int pbase = blockIdx.x * BN;
  const int phase = blockIdx.x & 7;     // kk rotation (de-sync CUs in L2)

  // stage the 4 layer biases into LDS (epilogues then have NO vmem ops,
  // so they can't be absorbed into the SGB VMEM groups)
  if (tid < 256) {
    lbias[tid]       = b1[tid];
    lbias[256 + tid] = b2[tid];
    lbias[512 + tid] = b3[tid];
    lbias[768 + tid] = b4[tid];
  }

  // ---- layer 0: K=3 linear + gabor, fp32 VALU; also fill skip cols ----
  {
    const int p = tid >> 3;             // 64 points, 8 threads each
    const int q = tid & 7;              // each thread: 32 units
    const int gp = pbase + p;
    float x0 = 0.f, x1 = 0.f, x2 = 0.f;
    if (gp < npts) {
      x0 = x[(size_t)gp * 3 + 0];
      x1 = x[(size_t)gp * 3 + 1];
      x2 = x[(size_t)gp * 3 + 2];
    }
#pragma unroll
    for (int ub = 0; ub < 32; ub += 8) {
      const int u0 = q * 32 + ub;
      f16x8 hv;
#pragma unroll
      for (int e = 0; e < 8; e++) {
        const int u = u0 + e;
        float lin = fmaf(x0, W0[u * 3 + 0],
                    fmaf(x1, W0[u * 3 + 1],
                    fmaf(x2, W0[u * 3 + 2], b0[u])));
        hv[e] = (_Float16)gabor_f(lin);
      }
      *(f16x8*)(bufA + swz(p, u0 * 2)) = hv;
    }
    // skip-concat cols 256..287 of bufA: [x0,x1,x2, 0...0]
    if (q < 4) {
      f16x8 xv = {(_Float16)0.f, (_Float16)0.f, (_Float16)0.f, (_Float16)0.f,
                  (_Float16)0.f, (_Float16)0.f, (_Float16)0.f, (_Float16)0.f};
      if (q == 0) { xv[0] = (_Float16)x0; xv[1] = (_Float16)x1; xv[2] = (_Float16)x2; }
      *(f16x8*)(bufA + swz(p, (256 + q * 8) * 2)) = xv;
    }
  }
  __syncthreads();

  const int lane = tid & 63;
  const int wid  = tid >> 6;            // 8 waves: 8 unit-slices, all points

  mfma_layer<8>(bufA, bufB, w1h, w1l, lbias,       lane, wid, phase);  // L1
  __syncthreads();
  mfma_layer<8>(bufB, bufA, w2h, w2l, lbias + 256, lane, wid, phase);  // L2
  __syncthreads();
  mfma_layer<9>(bufA, bufB, w3p, w3l, lbias + 512, lane, wid,
                phase > 8 ? 8 : phase);                                // L3 (KS=9)
  __syncthreads();
  mfma_layer<8>(bufB, bufA, w4h, w4l, lbias + 768, lane, wid, phase);  // L4
  __syncthreads();

  // ---- final linear: 3 outputs per point, fp32 VALU ----
  if (tid < BN * 3) {
    const int p = tid / 3;
    const int o = tid - p * 3;
    const int gp = pbase + p;
    if (gp < npts) {
      float a0 = bf[o], a1 = 0.f, a2 = 0.f, a3 = 0.f;
#pragma unroll 4
      for (int k = 0; k < 256; k += 8) {
        f16x8 hv = *(const f16x8*)(bufA + swz(p, k * 2));
        f32x4 wa = *(const f32x4*)(Wf + o * 256 + k);
        f32x4 wb = *(const f32x4*)(Wf + o * 256 + k + 4);
        a0 = fmaf((float)hv[0], wa[0], a0);
        a1 = fmaf((float)hv[1], wa[1], a1);
        a2 = fmaf((float)hv[2], wa[2], a2);
        a3 = fmaf((float)hv[3], wa[3], a3);
        a0 = fmaf((float)hv[4], wb[0], a0);
        a1 = fmaf((float)hv[5], wb[1], a1);
        a2 = fmaf((float)hv[6], wb[2], a2);
        a3 = fmaf((float)hv[7], wb[3], a3);
      }
      out[(size_t)gp * 3 + o] = (a0 + a1) + (a2 + a3);
    }
  }
}

// fp32 -> split fp16 (hi + lo residual) weight conversion, PACKED into the
// per-wave MFMA fragment order:
//   packed idx (within layer) = (((slice*KS + kk)*2 + i)*64 + lane)*8 + e
//   source: unit = slice*32 + i*16 + (lane&15); k = kk*32 + (lane>>4)*8 + e
// hi bank at [0, WELE), lo bank at [WELE, 2*WELE). Layer bases (halves):
//   L1 @0 (KS=8), L2 @65536 (KS=8), L4 @131072 (KS=8), L3 @196608 (KS=9,
//   K=288 zero-padded from 259).
extern "C" __global__ void conv_w(const float* __restrict__ W1,
                                  const float* __restrict__ W2,
                                  const float* __restrict__ W4,
                                  const float* __restrict__ W3,
                                  _Float16* __restrict__ wsh) {
  int idx = blockIdx.x * blockDim.x + threadIdx.x;
  if (idx >= WELE) return;

  int base, KS;
  const float* src = nullptr;
  int ldk = 256, kmax = 256;
  if (idx < 65536)       { base = 0;      KS = 8; src = W1; }
  else if (idx < 131072) { base = 65536;  KS = 8; src = W2; }
  else if (idx < 196608) { base = 131072; KS = 8; src = W4; }
  else                   { base = 196608; KS = 9; src = W3; ldk = 259; kmax = 259; }

  const int t    = idx - base;
  const int e    = t & 7;
  const int lane = (t >> 3) & 63;
  const int i    = (t >> 9) & 1;
  const int rem  = t >> 10;
  const int kk   = rem % KS;
  const int slice = rem / KS;

  const int unit = slice * 32 + i * 16 + (lane & 15);
  const int k    = kk * 32 + (lane >> 4) * 8 + e;

  const float w = (k < kmax) ? src[(size_t)unit * ldk + k] : 0.f;
  const _Float16 hi = (_Float16)w;
  const _Float16 lo = (_Float16)(w - (float)hi);
  wsh[idx] = hi;
  wsh[idx + WELE] = lo;
}

extern "C" void kernel_launch(void* const* d_in, const int* in_sizes, int n_in,
                              void* d_out, int out_size, void* d_ws, size_t ws_size,
                              hipStream_t stream) {
  const float* x  = (const float*)d_in[0];
  const float* W0 = (const float*)d_in[1];
  const float* b0 = (const float*)d_in[2];
  const float* W1 = (const float*)d_in[3];
  const float* b1 = (const float*)d_in[4];
  const float* W2 = (const float*)d_in[5];
  const float* b2 = (const float*)d_in[6];
  const float* W3 = (const float*)d_in[7];
  const float* b3 = (const float*)d_in[8];
  const float* W4 = (const float*)d_in[9];
  const float* b4 = (const float*)d_in[10];
  const float* Wf = (const float*)d_in[11];
  const float* bf = (const float*)d_in[12];
  float* out      = (float*)d_out;
  _Float16* wsh   = (_Float16*)d_ws;    // needs 2*WELE*2 B = 1081344 B

  const int npts = in_sizes[0] / 3;

  conv_w<<<(WELE + 511) / 512, 512, 0, stream>>>(W1, W2, W4, W3, wsh);

  const int nblk = (npts + BN - 1) / BN;
  inr_fused<<<nblk, 512, LDS_TOTAL, stream>>>(x, W0, b0, b1, b2, b3, b4,
                                              Wf, bf, wsh, out, npts);
}